// Round 2
// baseline (15733.693 us; speedup 1.0000x reference)
//
#include <hip/hip_runtime.h>

#define NSTEP 64

typedef short bf8 __attribute__((ext_vector_type(8)));          // 8 x bf16 (4 VGPRs) MFMA A/B frag
typedef float f32x16 __attribute__((ext_vector_type(16)));      // 32x32 MFMA C/D frag
typedef float f32x4 __attribute__((ext_vector_type(4)));
typedef unsigned int u32x4 __attribute__((ext_vector_type(4)));
typedef unsigned int u32x2 __attribute__((ext_vector_type(2)));

static __device__ __forceinline__ float asf(unsigned int u){ return __builtin_bit_cast(float, u); }
static __device__ __forceinline__ unsigned int asu(float f){ return __builtin_bit_cast(unsigned int, f); }

// round-to-nearest-even fp32 -> bf16 pair packed in one dword (a in low 16)
static __device__ __forceinline__ unsigned int pkbf(float a, float b){
  unsigned int ua = asu(a); unsigned int ub = asu(b);
  ua += 0x7FFFu + ((ua >> 16) & 1u);
  ub += 0x7FFFu + ((ub >> 16) & 1u);
  return (ua >> 16) | (ub & 0xFFFF0000u);
}

static __device__ __forceinline__ bf8 mkb(unsigned int a, unsigned int b, unsigned int c, unsigned int d){
  u32x4 u; u[0]=a; u[1]=b; u[2]=c; u[3]=d;
  return __builtin_bit_cast(bf8, u);
}

// ELU(p) = p>0 ? p : exp(p)-1   (exact for p>=0: exp2(0)=1)
static __device__ __forceinline__ float elu(float p){
  float e = __builtin_amdgcn_exp2f(fminf(p, 0.0f) * 1.4426950408889634f);
  return fmaxf(p, 0.0f) + (e - 1.0f);
}

// C-layout packs P[mt][q] (4 bf16 covering feature offsets 32*mt + 8*q + 4*hw + {0..3})
// -> B-fragments frag[kt] needing offsets 16*kt + 8*hw + {0..7}. Exchange lanes l <-> l^32.
static __device__ __forceinline__ void xch(const unsigned int P[2][4][2], int hw, bf8 frag[4]){
  #pragma unroll
  for(int kt=0; kt<4; kt++){
    const int mt = kt>>1;
    const int qa = (kt&1)*2;
    unsigned int a0 = P[mt][qa][0],   a1 = P[mt][qa][1];     // pack q = qa
    unsigned int b0 = P[mt][qa+1][0], b1v = P[mt][qa+1][1];  // pack q = qa+1
    unsigned int s0 = hw ? a0 : b0;
    unsigned int s1 = hw ? a1 : b1v;
    unsigned int r0 = (unsigned int)__shfl_xor((int)s0, 32, 64);
    unsigned int r1 = (unsigned int)__shfl_xor((int)s1, 32, 64);
    unsigned int d0 = hw ? r0  : a0;   // k offsets 8*q_run + 0..3
    unsigned int d1 = hw ? r1  : a1;
    unsigned int d2 = hw ? b0  : r0;   // k offsets 8*q_run + 4..7
    unsigned int d3 = hw ? b1v : r1;
    frag[kt] = mkb(d0,d1,d2,d3);
  }
}

// One wave = 32 batch rows, fully register-resident weights.
//  GEMM1: H^T[256 x 32] = W1[256x64] * Z^T[64x32]
//  GEMM2: K^T[64 x 32]  = W2[64x256] * ELU(H)^T
__global__ __launch_bounds__(256, 1) void ode_kernel(
    const void* __restrict__ xv,
    const void* __restrict__ tv,
    const void* __restrict__ W1v,
    const void* __restrict__ b1v,
    const void* __restrict__ W2v,
    const void* __restrict__ b2v,
    void* __restrict__ outv)
{
  __shared__ __align__(16) float b1s[256];
  __shared__ __align__(16) float b2s[64];

  const int tid = threadIdx.x;
  const int lid = tid & 63;

  // ---- runtime input-dtype detection (wave-uniform, deterministic) ----
  // bf16 weights are uniform(-1/8,1/8): every 16-bit half has bf16 exponent <= 124.
  // f32 weights: low halves are random mantissa bits -> some half decodes |v| >= 0.25.
  const unsigned int* w1u = (const unsigned int*)W1v;
  bool bad = false;
  #pragma unroll
  for(int i=0; i<2; i++){
    unsigned int d = w1u[i*64 + lid];
    unsigned int e0 = (d >> 7)  & 0xFFu;   // low-half bf16 exponent
    unsigned int e1 = (d >> 23) & 0xFFu;   // high-half bf16 exponent
    bad |= (e0 >= 125u) || (e1 >= 125u);
  }
  const bool f32in = (__ballot(bad) != 0ull);

  // ---- biases to shared (as f32) ----
  if(f32in){
    b1s[tid] = ((const float*)b1v)[tid];
    if(tid < 64) b2s[tid] = ((const float*)b2v)[tid];
  } else {
    b1s[tid] = asf((unsigned int)((const unsigned short*)b1v)[tid] << 16);
    if(tid < 64) b2s[tid] = asf((unsigned int)((const unsigned short*)b2v)[tid] << 16);
  }
  __syncthreads();

  const int wave = tid >> 6;
  const int ln   = tid & 31;        // MFMA n-index = this lane's batch row
  const int hw   = (tid >> 5) & 1;  // half-wave: k-group / m-subrow select
  const int r    = blockIdx.x * 128 + wave * 32 + ln;   // global batch row

  const float t  = f32in ? ((const float*)tv)[0]
                         : asf((unsigned int)((const unsigned short*)tv)[0] << 16);
  const float dt = t / (float)NSTEP;

  // ---- weight A-fragments (loaded once, live whole kernel) ----
  // A-frag 32x32x16: lane holds A[m = ln][k = 8*hw + j], j=0..7
  bf8 W1f[8][4];   // [u-tile 0..7][k-tile over 64 features]
  bf8 W2f[2][16];  // [f_out-tile 0..1][k-tile over 256 hidden]
  if(f32in){
    const float* W1 = (const float*)W1v;
    const float* W2 = (const float*)W2v;
    #pragma unroll
    for(int mt=0; mt<8; mt++){
      #pragma unroll
      for(int kt=0; kt<4; kt++){
        const float* p = W1 + (mt*32 + ln)*64 + kt*16 + hw*8;
        f32x4 a = *(const f32x4*)p;
        f32x4 b = *(const f32x4*)(p + 4);
        W1f[mt][kt] = mkb(pkbf(a[0],a[1]), pkbf(a[2],a[3]),
                          pkbf(b[0],b[1]), pkbf(b[2],b[3]));
      }
    }
    #pragma unroll
    for(int mt=0; mt<2; mt++){
      #pragma unroll
      for(int kt=0; kt<16; kt++){
        const float* p = W2 + (mt*32 + ln)*256 + kt*16 + hw*8;
        f32x4 a = *(const f32x4*)p;
        f32x4 b = *(const f32x4*)(p + 4);
        W2f[mt][kt] = mkb(pkbf(a[0],a[1]), pkbf(a[2],a[3]),
                          pkbf(b[0],b[1]), pkbf(b[2],b[3]));
      }
    }
  } else {
    const unsigned short* W1 = (const unsigned short*)W1v;
    const unsigned short* W2 = (const unsigned short*)W2v;
    #pragma unroll
    for(int mt=0; mt<8; mt++)
      #pragma unroll
      for(int kt=0; kt<4; kt++)
        W1f[mt][kt] = *(const bf8*)(W1 + (mt*32 + ln)*64 + kt*16 + hw*8);
    #pragma unroll
    for(int mt=0; mt<2; mt++)
      #pragma unroll
      for(int kt=0; kt<16; kt++)
        W2f[mt][kt] = *(const bf8*)(W2 + (mt*32 + ln)*256 + kt*16 + hw*8);
  }

  // ---- state Y in GEMM2 C-layout: Y[mt][4q+i] = y[r][f], f = 32*mt + 8*q + 4*hw + i ----
  float Y[2][16];
  if(f32in){
    const float* x = (const float*)xv;
    #pragma unroll
    for(int mt=0; mt<2; mt++){
      #pragma unroll
      for(int q=0; q<4; q++){
        f32x4 v = *(const f32x4*)(x + r*64 + mt*32 + q*8 + hw*4);
        Y[mt][4*q+0] = v[0]; Y[mt][4*q+1] = v[1];
        Y[mt][4*q+2] = v[2]; Y[mt][4*q+3] = v[3];
      }
    }
  } else {
    const unsigned short* x = (const unsigned short*)xv;
    #pragma unroll
    for(int mt=0; mt<2; mt++){
      #pragma unroll
      for(int q=0; q<4; q++){
        u32x2 v = *(const u32x2*)(x + r*64 + mt*32 + q*8 + hw*4);
        Y[mt][4*q+0] = asf(v[0] << 16);
        Y[mt][4*q+1] = asf(v[0] & 0xFFFF0000u);
        Y[mt][4*q+2] = asf(v[1] << 16);
        Y[mt][4*q+3] = asf(v[1] & 0xFFFF0000u);
      }
    }
  }

  f32x16 acc2[2];          // doubles as K (previous stage's f output)
  #pragma unroll
  for(int mt=0; mt<2; mt++)
    #pragma unroll
    for(int e=0; e<16; e++) acc2[mt][e] = 0.0f;

  float A[2][16];          // RK4 accumulator k1 + 2k2 + 2k3 + k4

  for(int step=0; step<NSTEP; step++){
    #pragma unroll
    for(int mt=0; mt<2; mt++)
      #pragma unroll
      for(int e=0; e<16; e++) A[mt][e] = 0.0f;

    for(int s=0; s<4; s++){
      const float c = (s==0) ? 0.0f : ((s==3) ? dt : 0.5f*dt);
      const float w = (s==1 || s==2) ? 2.0f : 1.0f;

      // z = Y + c*K  -> bf16 packs -> B-fragments for GEMM1
      unsigned int P[2][4][2];
      #pragma unroll
      for(int mt=0; mt<2; mt++){
        #pragma unroll
        for(int q=0; q<4; q++){
          float v0 = fmaf(c, acc2[mt][4*q+0], Y[mt][4*q+0]);
          float v1 = fmaf(c, acc2[mt][4*q+1], Y[mt][4*q+1]);
          float v2 = fmaf(c, acc2[mt][4*q+2], Y[mt][4*q+2]);
          float v3 = fmaf(c, acc2[mt][4*q+3], Y[mt][4*q+3]);
          P[mt][q][0] = pkbf(v0, v1);
          P[mt][q][1] = pkbf(v2, v3);
        }
      }
      bf8 zf[4];
      xch(P, hw, zf);

      // init GEMM2 accumulator with bias b2 (C-layout: f = 32*mt + 8*q + 4*hw + i)
      #pragma unroll
      for(int mt=0; mt<2; mt++){
        #pragma unroll
        for(int q=0; q<4; q++){
          f32x4 bv = *(const f32x4*)&b2s[mt*32 + q*8 + hw*4];
          acc2[mt][4*q+0] = bv[0];
          acc2[mt][4*q+1] = bv[1];
          acc2[mt][4*q+2] = bv[2];
          acc2[mt][4*q+3] = bv[3];
        }
      }

      // 4 chunks of 64 hidden units: GEMM1 -> ELU -> exchange -> GEMM2 partial
      #pragma unroll
      for(int ch=0; ch<4; ch++){
        f32x16 acc1[2];
        #pragma unroll
        for(int mtl=0; mtl<2; mtl++){
          #pragma unroll
          for(int q=0; q<4; q++){
            f32x4 bv = *(const f32x4*)&b1s[ch*64 + mtl*32 + q*8 + hw*4];
            acc1[mtl][4*q+0] = bv[0];
            acc1[mtl][4*q+1] = bv[1];
            acc1[mtl][4*q+2] = bv[2];
            acc1[mtl][4*q+3] = bv[3];
          }
        }
        #pragma unroll
        for(int kt=0; kt<4; kt++){
          #pragma unroll
          for(int mtl=0; mtl<2; mtl++){
            acc1[mtl] = __builtin_amdgcn_mfma_f32_32x32x16_bf16(
                W1f[ch*2+mtl][kt], zf[kt], acc1[mtl], 0, 0, 0);
          }
        }
        // ELU + pack to bf16
        unsigned int HP[2][4][2];
        #pragma unroll
        for(int mtl=0; mtl<2; mtl++){
          #pragma unroll
          for(int q=0; q<4; q++){
            float e0 = elu(acc1[mtl][4*q+0]);
            float e1 = elu(acc1[mtl][4*q+1]);
            float e2 = elu(acc1[mtl][4*q+2]);
            float e3 = elu(acc1[mtl][4*q+3]);
            HP[mtl][q][0] = pkbf(e0, e1);
            HP[mtl][q][1] = pkbf(e2, e3);
          }
        }
        bf8 hf[4];
        xch(HP, hw, hf);
        #pragma unroll
        for(int kl=0; kl<4; kl++){
          #pragma unroll
          for(int mt2=0; mt2<2; mt2++){
            acc2[mt2] = __builtin_amdgcn_mfma_f32_32x32x16_bf16(
                W2f[mt2][ch*4+kl], hf[kl], acc2[mt2], 0, 0, 0);
          }
        }
      }

      // RK accumulate: A += w * k_s   (k_s == acc2)
      #pragma unroll
      for(int mt=0; mt<2; mt++)
        #pragma unroll
        for(int e=0; e<16; e++) A[mt][e] = fmaf(w, acc2[mt][e], A[mt][e]);
    }

    const float g = dt * (1.0f/6.0f);
    #pragma unroll
    for(int mt=0; mt<2; mt++)
      #pragma unroll
      for(int e=0; e<16; e++) Y[mt][e] = fmaf(g, A[mt][e], Y[mt][e]);
  }

  // ---- store y in the detected dtype ----
  if(f32in){
    float* out = (float*)outv;
    #pragma unroll
    for(int mt=0; mt<2; mt++){
      #pragma unroll
      for(int q=0; q<4; q++){
        f32x4 v;
        v[0] = Y[mt][4*q+0]; v[1] = Y[mt][4*q+1];
        v[2] = Y[mt][4*q+2]; v[3] = Y[mt][4*q+3];
        *(f32x4*)(out + r*64 + mt*32 + q*8 + hw*4) = v;
      }
    }
  } else {
    unsigned short* out = (unsigned short*)outv;
    #pragma unroll
    for(int mt=0; mt<2; mt++){
      #pragma unroll
      for(int q=0; q<4; q++){
        u32x2 v;
        v[0] = pkbf(Y[mt][4*q+0], Y[mt][4*q+1]);
        v[1] = pkbf(Y[mt][4*q+2], Y[mt][4*q+3]);
        *(u32x2*)(out + r*64 + mt*32 + q*8 + hw*4) = v;
      }
    }
  }
}

extern "C" void kernel_launch(void* const* d_in, const int* in_sizes, int n_in,
                              void* d_out, int out_size, void* d_ws, size_t ws_size,
                              hipStream_t stream){
  // 262144 rows / 32 rows per wave / 4 waves per block = 2048 blocks
  hipLaunchKernelGGL(ode_kernel, dim3(2048), dim3(256), 0, stream,
                     d_in[0], d_in[1], d_in[2], d_in[3], d_in[4], d_in[5], d_out);
}